// Round 2
// baseline (46920.221 us; speedup 1.0000x reference)
//
#include <hip/hip_runtime.h>
#include <cstdint>
#include <cstddef>

// GRU_56607668961499: B=128, T=512, PRED=24, F=16, L=8, H=1024
// R2: single persistent kernel. Weights fp16 single-plane resident in LDS
// (staged once); h carried as fp16 hi+lo planes (~fp32 accurate); layer
// pipeline L0@t / L1i@t-1 / L1h@t-2, one grid barrier per tick.
// Roles: blocks 0-63 L0(+decoder), 64-127 L1-input GEMM, 128-191 L1-hidden
// GEMM + GRU epilogue, 192-207 FC head.

typedef _Float16 f16;
typedef f16 f16x8 __attribute__((ext_vector_type(8)));
typedef float f32x4 __attribute__((ext_vector_type(4)));

#define NB 208
#define NT 512
#define H_ 1024

__device__ __forceinline__ float sigm(float x) { return 1.0f / (1.0f + __expf(-x)); }

// ---------------- grid barrier (poison-safe: 0xAAAAAAAA < any phase) --------
__device__ __forceinline__ void gbar(int* flags, int* rel, int phase) {
  __threadfence();
  __syncthreads();
  int tid = threadIdx.x;
  if (tid == 0) {
    __hip_atomic_store(&flags[blockIdx.x], phase, __ATOMIC_RELEASE, __HIP_MEMORY_SCOPE_AGENT);
  }
  if (blockIdx.x == 0) {
    if (tid < NB) {
      while (__hip_atomic_load(&flags[tid], __ATOMIC_ACQUIRE, __HIP_MEMORY_SCOPE_AGENT) < phase)
        __builtin_amdgcn_s_sleep(8);
    }
    __syncthreads();
    if (tid == 0)
      __hip_atomic_store(rel, phase, __ATOMIC_RELEASE, __HIP_MEMORY_SCOPE_AGENT);
  }
  if (tid == 0) {
    while (__hip_atomic_load(rel, __ATOMIC_ACQUIRE, __HIP_MEMORY_SCOPE_AGENT) < phase)
      __builtin_amdgcn_s_sleep(8);
  }
  __syncthreads();
}

// ------------- stage 48 rows x 1024 K of fp32 weights -> fp16 LDS, swizzled --
// LDS offset(row, k8) = row*1024 + ((k8 ^ (row&7))<<3) fp16 units.
__device__ __forceinline__ void stage_W48(const float* __restrict__ W, int Ubase,
                                          f16* Wsh, int tid) {
  for (int i = tid; i < 6144; i += NT) {
    int row = i >> 7;      // 0..47  ([gate][unit])
    int k8 = i & 127;
    const float* src = W + ((size_t)((row >> 4) << 10) + Ubase + (row & 15)) * H_ + (k8 << 3);
    float4 a = *(const float4*)(src);
    float4 b = *(const float4*)(src + 4);
    f16x8 v;
    v[0] = (f16)a.x; v[1] = (f16)a.y; v[2] = (f16)a.z; v[3] = (f16)a.w;
    v[4] = (f16)b.x; v[5] = (f16)b.y; v[6] = (f16)b.z; v[7] = (f16)b.w;
    *(f16x8*)(Wsh + ((row << 10) + ((k8 ^ (row & 7)) << 3))) = v;
  }
}

// ------------- stage 48 rows x 24(->32) of small fp32 weights -> fp16 LDS ----
__device__ __forceinline__ void stage_wih(const float* __restrict__ W, int Ubase,
                                          f16* wih_s, int tid) {
  for (int i = tid; i < 48 * 32; i += NT) {
    int row = i >> 5, k = i & 31;
    float v = (k < 24) ? W[((size_t)((row >> 4) << 10) + Ubase + (row & 15)) * 24 + k] : 0.f;
    wih_s[row * 32 + k] = (f16)v;
  }
}

// ---------------- K=1024 3-gate GEMM, A = hi+lo fp16 planes ------------------
__device__ __forceinline__ void gemmK1024(const f16* __restrict__ Ahp,
                                          const f16* __restrict__ Alp,
                                          const f16* Wsh, int lane, int wv,
                                          f32x4& aR, f32x4& aZ, f32x4& aN) {
  const int q = lane >> 4, r = lane & 15;
  const f16* pa = Ahp + (size_t)(wv * 16 + r) * H_ + q * 8;
  const f16* pl = Alp + (size_t)(wv * 16 + r) * H_ + q * 8;
  const f16* w0 = Wsh + ((0 * 16 + r) << 10);
  const f16* w1 = Wsh + ((1 * 16 + r) << 10);
  const f16* w2 = Wsh + ((2 * 16 + r) << 10);
  const int sw = r & 7;
#pragma unroll 4
  for (int kt = 0; kt < 32; ++kt) {
    f16x8 Ah = *(const f16x8*)(pa + kt * 32);
    f16x8 Al = *(const f16x8*)(pl + kt * 32);
    int ko = (((kt * 4 + q) ^ sw) << 3);
    f16x8 B0 = *(const f16x8*)(w0 + ko);
    f16x8 B1 = *(const f16x8*)(w1 + ko);
    f16x8 B2 = *(const f16x8*)(w2 + ko);
    aR = __builtin_amdgcn_mfma_f32_16x16x32_f16(Ah, B0, aR, 0, 0, 0);
    aZ = __builtin_amdgcn_mfma_f32_16x16x32_f16(Ah, B1, aZ, 0, 0, 0);
    aN = __builtin_amdgcn_mfma_f32_16x16x32_f16(Ah, B2, aN, 0, 0, 0);
    aR = __builtin_amdgcn_mfma_f32_16x16x32_f16(Al, B0, aR, 0, 0, 0);
    aZ = __builtin_amdgcn_mfma_f32_16x16x32_f16(Al, B1, aZ, 0, 0, 0);
    aN = __builtin_amdgcn_mfma_f32_16x16x32_f16(Al, B2, aN, 0, 0, 0);
  }
}

// ---------------- x-side K=32 (padded 24) MFMA -------------------------------
__device__ __forceinline__ void gemmX(const f16* xs, const f16* wih_s, int lane, int wv,
                                      f32x4& aR, f32x4& aZ, f32x4& aNx) {
  const int q = lane >> 4, r = lane & 15;
  f16x8 Ax = *(const f16x8*)(xs + (wv * 16 + r) * 32 + q * 8);
  f16x8 B0 = *(const f16x8*)(wih_s + (0 * 16 + r) * 32 + q * 8);
  f16x8 B1 = *(const f16x8*)(wih_s + (1 * 16 + r) * 32 + q * 8);
  f16x8 B2 = *(const f16x8*)(wih_s + (2 * 16 + r) * 32 + q * 8);
  aR = __builtin_amdgcn_mfma_f32_16x16x32_f16(Ax, B0, aR, 0, 0, 0);
  aZ = __builtin_amdgcn_mfma_f32_16x16x32_f16(Ax, B1, aZ, 0, 0, 0);
  aNx = __builtin_amdgcn_mfma_f32_16x16x32_f16(Ax, B2, aNx, 0, 0, 0);
}

// ---------------- fused GRU nonlinearity + h store (hi/lo fp16) --------------
__device__ __forceinline__ void gru_epilogue(const f32x4& aR, const f32x4& aZ,
                                             const f32x4& aNh, const f32x4& aNx,
                                             float bR, float bZ, float bIN, float bHN,
                                             const f16* hph, const f16* hpl,
                                             f16* hoh, f16* hol, int u, int b0) {
#pragma unroll
  for (int i = 0; i < 4; ++i) {
    float rg = sigm(aR[i] + bR);
    float zg = sigm(aZ[i] + bZ);
    float ng = tanhf(aNx[i] + bIN + rg * (aNh[i] + bHN));
    size_t off = (size_t)(b0 + i) * H_ + u;
    float hp = (float)hph[off] + (float)hpl[off];
    float hn = (1.f - zg) * ng + zg * hp;
    f16 hh = (f16)hn;
    hoh[off] = hh;
    hol[off] = (f16)(hn - (float)hh);
  }
}

// ---------------- FC head: p = h @ fcW.T + fcb (16 blocks x 8 rows) ----------
__device__ __forceinline__ void fc_step(const f16* hh, const f16* hl,
                                        const float* fcW_s, float fcbv, int fcblk,
                                        int tid, float* out_slice, float* pdst) {
  int b_loc = tid >> 6;            // 0..7
  int l = (tid >> 3) & 7;
  int strip = tid & 7;             // lanes 0..7 within wave
  int b = fcblk * 8 + b_loc;
  const f16* ph = hh + (size_t)b * H_ + strip * 128;
  const f16* pl = hl + (size_t)b * H_ + strip * 128;
  const float* pw = fcW_s + l * H_ + strip * 128;
  float s = 0.f;
  for (int j = 0; j < 128; j += 8) {
    f16x8 a = *(const f16x8*)(ph + j);
    f16x8 c = *(const f16x8*)(pl + j);
#pragma unroll
    for (int e = 0; e < 8; ++e) s += ((float)a[e] + (float)c[e]) * pw[j + e];
  }
  s += __shfl_xor(s, 1);
  s += __shfl_xor(s, 2);
  s += __shfl_xor(s, 4);
  if (strip == 0) {
    float v = s + fcbv;
    out_slice[b * 8 + l] = v;
    pdst[b * 8 + l] = v;
  }
}

// ------------------------------- persistent kernel ---------------------------
__global__ __launch_bounds__(NT, 2) void gru_persist(
    const float* __restrict__ feats, const float* __restrict__ labels,
    const float* __restrict__ wih0, const float* __restrict__ whh0,
    const float* __restrict__ bih0, const float* __restrict__ bhh0,
    const float* __restrict__ wih1, const float* __restrict__ whh1,
    const float* __restrict__ bih1, const float* __restrict__ bhh1,
    const float* __restrict__ dwih, const float* __restrict__ dwhh,
    const float* __restrict__ dbih, const float* __restrict__ dbhh,
    const float* __restrict__ fcW, const float* __restrict__ fcb,
    float* __restrict__ out, char* ws) {
  int* flags = (int*)ws;
  int* rel = (int*)(ws + 4096);
  f16* h0b = (f16*)(ws + 8192);                   // [par][plane][128][1024]
  f16* h1b = h0b + 2 * 2 * 128 * H_;              // same layout (also decoder h)
  float* gi = (float*)(ws + 8192 + 2097152);      // [par][3072][128] f32
  float* pbuf = (float*)(ws + 8192 + 2097152 + 3145728);  // [par][128*8]

  const int bid = blockIdx.x, tid = threadIdx.x;
  const int lane = tid & 63, wv = tid >> 6;
  const int q = lane >> 4, r = lane & 15;
  const int role = bid >> 6;                      // 0:L0 1:L1i 2:L1h 3:FC
  const int Ubase = (bid & 63) << 4;
  const int u = Ubase + r;
  const int b0 = wv * 16 + q * 4;

  __shared__ __align__(16) unsigned char smem[109568];
  f16* Wsh = (f16*)smem;                          // 48 x 1024 fp16 (96 KB)
  f16* xs = (f16*)(smem + 98304);                 // 128 x 32 fp16
  f16* wih_s = (f16*)(smem + 106496);             // 48 x 32 fp16
  float* fcW_s = (float*)smem;                    // role 3: 8 x 1024 f32

  // zero h state (both h0/h1 parities+planes = 2 MB contiguous)
  {
    uint32_t* zp = (uint32_t*)h0b;
    for (int i = bid * NT + tid; i < 524288; i += NB * NT) zp[i] = 0;
  }
  // zero xs once (tail k8=3 stays zero forever)
  for (int i = tid; i < 2048; i += NT) ((uint32_t*)xs)[i] = 0;

  // stage persistent weights
  if (role == 0) { stage_W48(whh0, Ubase, Wsh, tid); stage_wih(wih0, Ubase, wih_s, tid); }
  else if (role == 1) stage_W48(wih1, Ubase, Wsh, tid);
  else if (role == 2) stage_W48(whh1, Ubase, Wsh, tid);
  else for (int i = tid; i < 8192; i += NT) fcW_s[i] = fcW[i];

  // biases in registers (combined where possible)
  float bR = 0.f, bZ = 0.f, bIN = 0.f, bHN = 0.f;
  if (role == 0) {
    bR = bih0[u] + bhh0[u]; bZ = bih0[1024 + u] + bhh0[1024 + u];
    bIN = bih0[2048 + u];   bHN = bhh0[2048 + u];
  } else if (role == 2) {
    bR = bih1[u] + bhh1[u]; bZ = bih1[1024 + u] + bhh1[1024 + u];
    bIN = bih1[2048 + u];   bHN = bhh1[2048 + u];
  }
  float fcbv = (role == 3) ? fcb[(tid >> 3) & 7] : 0.f;

  int ph = 1;
  gbar(flags, rel, ph++);   // init visible

  // =================== encoder: 514 pipelined super-ticks ====================
  for (int s = 0; s < 514; ++s) {
    if (role == 0 && s < 512) {
      // stage x[s] = [feats[:,s,:16], labels[:,s,:8], 0pad] as fp16
      {
        int row = tid >> 2, k8 = tid & 3;
        if (k8 < 2) {
          const float* fp = feats + ((size_t)row * 535 + s) * 16 + k8 * 8;
          float4 a = *(const float4*)fp; float4 b = *(const float4*)(fp + 4);
          f16x8 v;
          v[0] = (f16)a.x; v[1] = (f16)a.y; v[2] = (f16)a.z; v[3] = (f16)a.w;
          v[4] = (f16)b.x; v[5] = (f16)b.y; v[6] = (f16)b.z; v[7] = (f16)b.w;
          *(f16x8*)(xs + row * 32 + k8 * 8) = v;
        } else if (k8 == 2) {
          const float* lp = labels + ((size_t)row * 512 + s) * 8;
          float4 a = *(const float4*)lp; float4 b = *(const float4*)(lp + 4);
          f16x8 v;
          v[0] = (f16)a.x; v[1] = (f16)a.y; v[2] = (f16)a.z; v[3] = (f16)a.w;
          v[4] = (f16)b.x; v[5] = (f16)b.y; v[6] = (f16)b.z; v[7] = (f16)b.w;
          *(f16x8*)(xs + row * 32 + 16) = v;
        }
      }
      __syncthreads();
      const f16* hph = h0b + (size_t)((s + 1) & 1) * 262144;
      const f16* hpl = hph + 131072;
      f16* hoh = h0b + (size_t)(s & 1) * 262144;
      f16* hol = hoh + 131072;
      f32x4 aR = {0,0,0,0}, aZ = {0,0,0,0}, aN = {0,0,0,0}, aNx = {0,0,0,0};
      gemmK1024(hph, hpl, Wsh, lane, wv, aR, aZ, aN);
      gemmX(xs, wih_s, lane, wv, aR, aZ, aNx);
      gru_epilogue(aR, aZ, aN, aNx, bR, bZ, bIN, bHN, hph, hpl, hoh, hol, u, b0);
    } else if (role == 1 && s >= 1 && s <= 512) {
      // gi1[s-1] = h0[s-1] @ wih1^T (raw, biases added by L1h)
      const f16* hph = h0b + (size_t)((s - 1) & 1) * 262144;
      const f16* hpl = hph + 131072;
      f32x4 aR = {0,0,0,0}, aZ = {0,0,0,0}, aN = {0,0,0,0};
      gemmK1024(hph, hpl, Wsh, lane, wv, aR, aZ, aN);
      float* dst = gi + (size_t)((s - 1) & 1) * 393216;
      *(f32x4*)(dst + (size_t)u * 128 + b0) = aR;
      *(f32x4*)(dst + (size_t)(1024 + u) * 128 + b0) = aZ;
      *(f32x4*)(dst + (size_t)(2048 + u) * 128 + b0) = aN;
    } else if (role == 2 && s >= 2) {
      // h1[s-2] from h1[s-3] and gi1[s-2]
      const f16* hph = h1b + (size_t)((s - 1) & 1) * 262144;
      const f16* hpl = hph + 131072;
      f16* hoh = h1b + (size_t)(s & 1) * 262144;
      f16* hol = hoh + 131072;
      f32x4 aR = {0,0,0,0}, aZ = {0,0,0,0}, aN = {0,0,0,0};
      gemmK1024(hph, hpl, Wsh, lane, wv, aR, aZ, aN);
      const float* gp = gi + (size_t)(s & 1) * 393216;
      f32x4 gR = *(const f32x4*)(gp + (size_t)u * 128 + b0);
      f32x4 gZ = *(const f32x4*)(gp + (size_t)(1024 + u) * 128 + b0);
      f32x4 gN = *(const f32x4*)(gp + (size_t)(2048 + u) * 128 + b0);
      f32x4 tR = aR + gR, tZ = aZ + gZ;
      gru_epilogue(tR, tZ, aN, gN, bR, bZ, bIN, bHN, hph, hpl, hoh, hol, u, b0);
    }
    gbar(flags, rel, ph++);
  }

  // =================== decoder prologue: ps + weight swap ====================
  if (role == 3) {
    const f16* hf = h1b + 262144;  // h1[511] in parity 1
    fc_step(hf, hf + 131072, fcW_s, fcbv, bid - 192, tid, out, pbuf + 1024);
  }
  if (role == 0) {
    stage_W48(dwhh, Ubase, Wsh, tid);
    stage_wih(dwih, Ubase, wih_s, tid);
    bR = dbih[u] + dbhh[u]; bZ = dbih[1024 + u] + dbhh[1024 + u];
    bIN = dbih[2048 + u];   bHN = dbhh[2048 + u];
  }
  gbar(flags, rel, ph++);

  // =================== decoder: 23 free-running ticks ========================
  for (int d = 0; d < 23; ++d) {
    if (role == 0) {
      {
        int row = tid >> 2, k8 = tid & 3;
        if (k8 < 2) {
          const float* fp = feats + ((size_t)row * 535 + 512 + d) * 16 + k8 * 8;
          float4 a = *(const float4*)fp; float4 b = *(const float4*)(fp + 4);
          f16x8 v;
          v[0] = (f16)a.x; v[1] = (f16)a.y; v[2] = (f16)a.z; v[3] = (f16)a.w;
          v[4] = (f16)b.x; v[5] = (f16)b.y; v[6] = (f16)b.z; v[7] = (f16)b.w;
          *(f16x8*)(xs + row * 32 + k8 * 8) = v;
        } else if (k8 == 2) {
          const float* pp = pbuf + (size_t)((d + 1) & 1) * 1024 + row * 8;
          float4 a = *(const float4*)pp; float4 b = *(const float4*)(pp + 4);
          f16x8 v;
          v[0] = (f16)a.x; v[1] = (f16)a.y; v[2] = (f16)a.z; v[3] = (f16)a.w;
          v[4] = (f16)b.x; v[5] = (f16)b.y; v[6] = (f16)b.z; v[7] = (f16)b.w;
          *(f16x8*)(xs + row * 32 + 16) = v;
        }
      }
      __syncthreads();
      const f16* hph = h1b + (size_t)((d + 1) & 1) * 262144;
      const f16* hpl = hph + 131072;
      f16* hoh = h1b + (size_t)(d & 1) * 262144;
      f16* hol = hoh + 131072;
      f32x4 aR = {0,0,0,0}, aZ = {0,0,0,0}, aN = {0,0,0,0}, aNx = {0,0,0,0};
      gemmK1024(hph, hpl, Wsh, lane, wv, aR, aZ, aN);
      gemmX(xs, wih_s, lane, wv, aR, aZ, aNx);
      gru_epilogue(aR, aZ, aN, aNx, bR, bZ, bIN, bHN, hph, hpl, hoh, hol, u, b0);
    }
    gbar(flags, rel, ph++);
    if (role == 3) {
      const f16* hd = h1b + (size_t)(d & 1) * 262144;
      fc_step(hd, hd + 131072, fcW_s, fcbv, bid - 192, tid,
              out + (size_t)(d + 1) * 1024, pbuf + (size_t)(d & 1) * 1024);
    }
    gbar(flags, rel, ph++);
  }
}

// ------------------------------------ host -----------------------------------
extern "C" void kernel_launch(void* const* d_in, const int* in_sizes, int n_in,
                              void* d_out, int out_size, void* d_ws, size_t ws_size,
                              hipStream_t stream) {
  (void)in_sizes; (void)n_in; (void)out_size; (void)ws_size;
  gru_persist<<<NB, NT, 0, stream>>>(
      (const float*)d_in[0], (const float*)d_in[1],
      (const float*)d_in[4], (const float*)d_in[5],
      (const float*)d_in[6], (const float*)d_in[7],
      (const float*)d_in[8], (const float*)d_in[9],
      (const float*)d_in[10], (const float*)d_in[11],
      (const float*)d_in[12], (const float*)d_in[13],
      (const float*)d_in[14], (const float*)d_in[15],
      (const float*)d_in[16], (const float*)d_in[17],
      (float*)d_out, (char*)d_ws);
}

// Round 4
// 14694.894 us; speedup vs baseline: 3.1930x; 3.1930x over previous
//
#include <hip/hip_runtime.h>
#include <cstdint>
#include <cstddef>

// GRU_56607668961499: B=128, T=512, PRED=24, F=16, L=8, H=1024
// R4: persistent kernel, R2 dataflow (plain writeback stores — proven correct)
// + cheap barrier: ONE release fence (buffer_wbl2) + ONE acquire fence
// (buffer_inv) per block per barrier, RELAXED polls in between.
// R2 failed perf because ACQUIRE polls emitted buffer_inv per spin iteration
// (device-wide L2 invalidate storm -> 80us/barrier). R3 failed correctness
// because sc0|sc1 store vmcnt-ack does not imply L3 visibility (flags raced
// ahead of data). This round uses the LLVM-blessed release/acquire sequences,
// exactly once per barrier.

typedef _Float16 f16;
typedef f16 f16x8 __attribute__((ext_vector_type(8)));
typedef float f32x4 __attribute__((ext_vector_type(4)));

#define NB 208
#define NT 512
#define H_ 1024

__device__ __forceinline__ float sigm(float x) { return 1.0f / (1.0f + __expf(-x)); }

// ---------------- grid barrier: one wbl2 + one inv per block -----------------
__device__ __forceinline__ void gbar(int* flags, int* rel, int phase) {
  __syncthreads();   // compiler drains vmcnt/lgkmcnt for every wave before s_barrier
  const int tid = threadIdx.x;
  if (blockIdx.x == 0) {
    if (tid == 0) {
      __builtin_amdgcn_fence(__ATOMIC_RELEASE, "agent");  // wbl2 + drain
      __hip_atomic_store(&flags[0], phase, __ATOMIC_RELAXED, __HIP_MEMORY_SCOPE_AGENT);
    }
    if (tid < NB) {
      while (__hip_atomic_load(&flags[tid], __ATOMIC_RELAXED, __HIP_MEMORY_SCOPE_AGENT) < phase)
        __builtin_amdgcn_s_sleep(1);
    }
    __syncthreads();
    if (tid == 0) {
      __hip_atomic_store(rel, phase, __ATOMIC_RELAXED, __HIP_MEMORY_SCOPE_AGENT);
      __builtin_amdgcn_fence(__ATOMIC_ACQUIRE, "agent");  // single buffer_inv
    }
  } else {
    if (tid == 0) {
      __builtin_amdgcn_fence(__ATOMIC_RELEASE, "agent");  // wbl2 + drain
      __hip_atomic_store(&flags[blockIdx.x], phase, __ATOMIC_RELAXED, __HIP_MEMORY_SCOPE_AGENT);
      while (__hip_atomic_load(rel, __ATOMIC_RELAXED, __HIP_MEMORY_SCOPE_AGENT) < phase)
        __builtin_amdgcn_s_sleep(1);
      __builtin_amdgcn_fence(__ATOMIC_ACQUIRE, "agent");  // single buffer_inv
    }
  }
  __syncthreads();   // all waves wait until tid0's inv completed
}

// ------------- stage 48 rows x 1024 K of fp32 weights -> fp16 LDS, swizzled --
__device__ __forceinline__ void stage_W48(const float* __restrict__ W, int Ubase,
                                          f16* Wsh, int tid) {
  for (int i = tid; i < 6144; i += NT) {
    int row = i >> 7;      // 0..47  ([gate][unit])
    int k8 = i & 127;
    const float* src = W + ((size_t)((row >> 4) << 10) + Ubase + (row & 15)) * H_ + (k8 << 3);
    float4 a = *(const float4*)(src);
    float4 b = *(const float4*)(src + 4);
    f16x8 v;
    v[0] = (f16)a.x; v[1] = (f16)a.y; v[2] = (f16)a.z; v[3] = (f16)a.w;
    v[4] = (f16)b.x; v[5] = (f16)b.y; v[6] = (f16)b.z; v[7] = (f16)b.w;
    *(f16x8*)(Wsh + ((row << 10) + ((k8 ^ (row & 7)) << 3))) = v;
  }
}

__device__ __forceinline__ void stage_wih(const float* __restrict__ W, int Ubase,
                                          f16* wih_s, int tid) {
  for (int i = tid; i < 48 * 32; i += NT) {
    int row = i >> 5, k = i & 31;
    float v = (k < 24) ? W[((size_t)((row >> 4) << 10) + Ubase + (row & 15)) * 24 + k] : 0.f;
    wih_s[row * 32 + k] = (f16)v;
  }
}

// ---------------- K=1024 3-gate GEMM, A = hi+lo fp16 planes ------------------
__device__ __forceinline__ void gemmK1024(const f16* __restrict__ Ahp,
                                          const f16* __restrict__ Alp,
                                          const f16* Wsh, int lane, int wv,
                                          f32x4& aR, f32x4& aZ, f32x4& aN) {
  const int q = lane >> 4, r = lane & 15;
  const f16* pa = Ahp + (size_t)(wv * 16 + r) * H_ + q * 8;
  const f16* pl = Alp + (size_t)(wv * 16 + r) * H_ + q * 8;
  const f16* w0 = Wsh + ((0 * 16 + r) << 10);
  const f16* w1 = Wsh + ((1 * 16 + r) << 10);
  const f16* w2 = Wsh + ((2 * 16 + r) << 10);
  const int sw = r & 7;
#pragma unroll 4
  for (int kt = 0; kt < 32; ++kt) {
    f16x8 Ah = *(const f16x8*)(pa + kt * 32);
    f16x8 Al = *(const f16x8*)(pl + kt * 32);
    int ko = (((kt * 4 + q) ^ sw) << 3);
    f16x8 B0 = *(const f16x8*)(w0 + ko);
    f16x8 B1 = *(const f16x8*)(w1 + ko);
    f16x8 B2 = *(const f16x8*)(w2 + ko);
    aR = __builtin_amdgcn_mfma_f32_16x16x32_f16(Ah, B0, aR, 0, 0, 0);
    aZ = __builtin_amdgcn_mfma_f32_16x16x32_f16(Ah, B1, aZ, 0, 0, 0);
    aN = __builtin_amdgcn_mfma_f32_16x16x32_f16(Ah, B2, aN, 0, 0, 0);
    aR = __builtin_amdgcn_mfma_f32_16x16x32_f16(Al, B0, aR, 0, 0, 0);
    aZ = __builtin_amdgcn_mfma_f32_16x16x32_f16(Al, B1, aZ, 0, 0, 0);
    aN = __builtin_amdgcn_mfma_f32_16x16x32_f16(Al, B2, aN, 0, 0, 0);
  }
}

// ---------------- x-side K=32 (padded 24) MFMA -------------------------------
__device__ __forceinline__ void gemmX(const f16* xs, const f16* wih_s, int lane, int wv,
                                      f32x4& aR, f32x4& aZ, f32x4& aNx) {
  const int q = lane >> 4, r = lane & 15;
  f16x8 Ax = *(const f16x8*)(xs + (wv * 16 + r) * 32 + q * 8);
  f16x8 B0 = *(const f16x8*)(wih_s + (0 * 16 + r) * 32 + q * 8);
  f16x8 B1 = *(const f16x8*)(wih_s + (1 * 16 + r) * 32 + q * 8);
  f16x8 B2 = *(const f16x8*)(wih_s + (2 * 16 + r) * 32 + q * 8);
  aR = __builtin_amdgcn_mfma_f32_16x16x32_f16(Ax, B0, aR, 0, 0, 0);
  aZ = __builtin_amdgcn_mfma_f32_16x16x32_f16(Ax, B1, aZ, 0, 0, 0);
  aNx = __builtin_amdgcn_mfma_f32_16x16x32_f16(Ax, B2, aNx, 0, 0, 0);
}

// ---------------- fused GRU nonlinearity + h store (hi/lo fp16) --------------
__device__ __forceinline__ void gru_epilogue(const f32x4& aR, const f32x4& aZ,
                                             const f32x4& aNh, const f32x4& aNx,
                                             float bR, float bZ, float bIN, float bHN,
                                             const f16* hph, const f16* hpl,
                                             f16* hoh, f16* hol, int u, int b0) {
#pragma unroll
  for (int i = 0; i < 4; ++i) {
    float rg = sigm(aR[i] + bR);
    float zg = sigm(aZ[i] + bZ);
    float ng = tanhf(aNx[i] + bIN + rg * (aNh[i] + bHN));
    size_t off = (size_t)(b0 + i) * H_ + u;
    float hp = (float)hph[off] + (float)hpl[off];
    float hn = (1.f - zg) * ng + zg * hp;
    f16 hh = (f16)hn;
    hoh[off] = hh;
    hol[off] = (f16)(hn - (float)hh);
  }
}

// ---------------- FC head: p = h @ fcW.T + fcb (16 blocks x 8 rows) ----------
__device__ __forceinline__ void fc_step(const f16* hh, const f16* hl,
                                        const float* fcW_s, float fcbv, int fcblk,
                                        int tid, float* out_slice, float* pdst) {
  int b_loc = tid >> 6;            // 0..7
  int l = (tid >> 3) & 7;
  int strip = tid & 7;             // lanes 0..7 within wave
  int b = fcblk * 8 + b_loc;
  const f16* ph = hh + (size_t)b * H_ + strip * 128;
  const f16* pl = hl + (size_t)b * H_ + strip * 128;
  const float* pw = fcW_s + l * H_ + strip * 128;
  float s = 0.f;
  for (int j = 0; j < 128; j += 8) {
    f16x8 a = *(const f16x8*)(ph + j);
    f16x8 c = *(const f16x8*)(pl + j);
#pragma unroll
    for (int e = 0; e < 8; ++e) s += ((float)a[e] + (float)c[e]) * pw[j + e];
  }
  s += __shfl_xor(s, 1);
  s += __shfl_xor(s, 2);
  s += __shfl_xor(s, 4);
  if (strip == 0) {
    float v = s + fcbv;
    out_slice[b * 8 + l] = v;
    pdst[b * 8 + l] = v;
  }
}

// ------------------------------- persistent kernel ---------------------------
__global__ __launch_bounds__(NT, 2) void gru_persist(
    const float* __restrict__ feats, const float* __restrict__ labels,
    const float* __restrict__ wih0, const float* __restrict__ whh0,
    const float* __restrict__ bih0, const float* __restrict__ bhh0,
    const float* __restrict__ wih1, const float* __restrict__ whh1,
    const float* __restrict__ bih1, const float* __restrict__ bhh1,
    const float* __restrict__ dwih, const float* __restrict__ dwhh,
    const float* __restrict__ dbih, const float* __restrict__ dbhh,
    const float* __restrict__ fcW, const float* __restrict__ fcb,
    float* __restrict__ out, char* ws) {
  int* flags = (int*)ws;
  int* rel = (int*)(ws + 4096);
  f16* h0b = (f16*)(ws + 8192);                   // [par][plane][128][1024]
  f16* h1b = h0b + 2 * 2 * 128 * H_;              // same layout (also decoder h)
  float* gi = (float*)(ws + 8192 + 2097152);      // [par][3072][128] f32
  float* pbuf = (float*)(ws + 8192 + 2097152 + 3145728);  // [par][128*8]

  const int bid = blockIdx.x, tid = threadIdx.x;
  const int lane = tid & 63, wv = tid >> 6;
  const int q = lane >> 4, r = lane & 15;
  const int role = bid >> 6;                      // 0:L0 1:L1i 2:L1h 3:FC
  const int Ubase = (bid & 63) << 4;
  const int u = Ubase + r;
  const int b0 = wv * 16 + q * 4;

  __shared__ __align__(16) unsigned char smem[109568];
  f16* Wsh = (f16*)smem;                          // 48 x 1024 fp16 (96 KB)
  f16* xs = (f16*)(smem + 98304);                 // 128 x 32 fp16
  f16* wih_s = (f16*)(smem + 106496);             // 48 x 32 fp16
  float* fcW_s = (float*)smem;                    // role 3: 8 x 1024 f32

  // zero h state (both h0/h1 parities+planes = 2 MB contiguous), plain stores
  {
    uint32_t* zp = (uint32_t*)h0b;
    for (int i = bid * NT + tid; i < 524288; i += NB * NT) zp[i] = 0;
  }
  for (int i = tid; i < 2048; i += NT) ((uint32_t*)xs)[i] = 0;

  // stage persistent weights
  if (role == 0) { stage_W48(whh0, Ubase, Wsh, tid); stage_wih(wih0, Ubase, wih_s, tid); }
  else if (role == 1) stage_W48(wih1, Ubase, Wsh, tid);
  else if (role == 2) stage_W48(whh1, Ubase, Wsh, tid);
  else for (int i = tid; i < 8192; i += NT) fcW_s[i] = fcW[i];

  float bR = 0.f, bZ = 0.f, bIN = 0.f, bHN = 0.f;
  if (role == 0) {
    bR = bih0[u] + bhh0[u]; bZ = bih0[1024 + u] + bhh0[1024 + u];
    bIN = bih0[2048 + u];   bHN = bhh0[2048 + u];
  } else if (role == 2) {
    bR = bih1[u] + bhh1[u]; bZ = bih1[1024 + u] + bhh1[1024 + u];
    bIN = bih1[2048 + u];   bHN = bhh1[2048 + u];
  }
  float fcbv = (role == 3) ? fcb[(tid >> 3) & 7] : 0.f;

  int ph = 1;
  gbar(flags, rel, ph++);   // init visible

  // =================== encoder: 514 pipelined super-ticks ====================
  for (int s = 0; s < 514; ++s) {
    if (role == 0 && s < 512) {
      {
        int row = tid >> 2, k8 = tid & 3;
        if (k8 < 2) {
          const float* fp = feats + ((size_t)row * 535 + s) * 16 + k8 * 8;
          float4 a = *(const float4*)fp; float4 b = *(const float4*)(fp + 4);
          f16x8 v;
          v[0] = (f16)a.x; v[1] = (f16)a.y; v[2] = (f16)a.z; v[3] = (f16)a.w;
          v[4] = (f16)b.x; v[5] = (f16)b.y; v[6] = (f16)b.z; v[7] = (f16)b.w;
          *(f16x8*)(xs + row * 32 + k8 * 8) = v;
        } else if (k8 == 2) {
          const float* lp = labels + ((size_t)row * 512 + s) * 8;
          float4 a = *(const float4*)lp; float4 b = *(const float4*)(lp + 4);
          f16x8 v;
          v[0] = (f16)a.x; v[1] = (f16)a.y; v[2] = (f16)a.z; v[3] = (f16)a.w;
          v[4] = (f16)b.x; v[5] = (f16)b.y; v[6] = (f16)b.z; v[7] = (f16)b.w;
          *(f16x8*)(xs + row * 32 + 16) = v;
        }
      }
      __syncthreads();
      const f16* hph = h0b + (size_t)((s + 1) & 1) * 262144;
      const f16* hpl = hph + 131072;
      f16* hoh = h0b + (size_t)(s & 1) * 262144;
      f16* hol = hoh + 131072;
      f32x4 aR = {0,0,0,0}, aZ = {0,0,0,0}, aN = {0,0,0,0}, aNx = {0,0,0,0};
      gemmK1024(hph, hpl, Wsh, lane, wv, aR, aZ, aN);
      gemmX(xs, wih_s, lane, wv, aR, aZ, aNx);
      gru_epilogue(aR, aZ, aN, aNx, bR, bZ, bIN, bHN, hph, hpl, hoh, hol, u, b0);
    } else if (role == 1 && s >= 1 && s <= 512) {
      const f16* hph = h0b + (size_t)((s - 1) & 1) * 262144;
      const f16* hpl = hph + 131072;
      f32x4 aR = {0,0,0,0}, aZ = {0,0,0,0}, aN = {0,0,0,0};
      gemmK1024(hph, hpl, Wsh, lane, wv, aR, aZ, aN);
      float* dst = gi + (size_t)((s - 1) & 1) * 393216;
      *(f32x4*)(dst + (size_t)u * 128 + b0) = aR;
      *(f32x4*)(dst + (size_t)(1024 + u) * 128 + b0) = aZ;
      *(f32x4*)(dst + (size_t)(2048 + u) * 128 + b0) = aN;
    } else if (role == 2 && s >= 2) {
      const f16* hph = h1b + (size_t)((s - 1) & 1) * 262144;
      const f16* hpl = hph + 131072;
      f16* hoh = h1b + (size_t)(s & 1) * 262144;
      f16* hol = hoh + 131072;
      f32x4 aR = {0,0,0,0}, aZ = {0,0,0,0}, aN = {0,0,0,0};
      gemmK1024(hph, hpl, Wsh, lane, wv, aR, aZ, aN);
      const float* gp = gi + (size_t)(s & 1) * 393216;
      f32x4 gR = *(const f32x4*)(gp + (size_t)u * 128 + b0);
      f32x4 gZ = *(const f32x4*)(gp + (size_t)(1024 + u) * 128 + b0);
      f32x4 gN = *(const f32x4*)(gp + (size_t)(2048 + u) * 128 + b0);
      f32x4 tR = aR + gR, tZ = aZ + gZ;
      gru_epilogue(tR, tZ, aN, gN, bR, bZ, bIN, bHN, hph, hpl, hoh, hol, u, b0);
    }
    gbar(flags, rel, ph++);
  }

  // =================== decoder prologue: ps + weight swap ====================
  if (role == 3) {
    const f16* hf = h1b + 262144;  // h1[511] in parity 1
    fc_step(hf, hf + 131072, fcW_s, fcbv, bid - 192, tid, out, pbuf + 1024);
  }
  if (role == 0) {
    stage_W48(dwhh, Ubase, Wsh, tid);
    stage_wih(dwih, Ubase, wih_s, tid);
    bR = dbih[u] + dbhh[u]; bZ = dbih[1024 + u] + dbhh[1024 + u];
    bIN = dbih[2048 + u];   bHN = dbhh[2048 + u];
  }
  gbar(flags, rel, ph++);

  // =================== decoder: 23 free-running ticks ========================
  for (int d = 0; d < 23; ++d) {
    if (role == 0) {
      {
        int row = tid >> 2, k8 = tid & 3;
        if (k8 < 2) {
          const float* fp = feats + ((size_t)row * 535 + 512 + d) * 16 + k8 * 8;
          float4 a = *(const float4*)fp; float4 b = *(const float4*)(fp + 4);
          f16x8 v;
          v[0] = (f16)a.x; v[1] = (f16)a.y; v[2] = (f16)a.z; v[3] = (f16)a.w;
          v[4] = (f16)b.x; v[5] = (f16)b.y; v[6] = (f16)b.z; v[7] = (f16)b.w;
          *(f16x8*)(xs + row * 32 + k8 * 8) = v;
        } else if (k8 == 2) {
          const float* pp = pbuf + (size_t)((d + 1) & 1) * 1024 + row * 8;
          float4 a = *(const float4*)pp; float4 b = *(const float4*)(pp + 4);
          f16x8 v;
          v[0] = (f16)a.x; v[1] = (f16)a.y; v[2] = (f16)a.z; v[3] = (f16)a.w;
          v[4] = (f16)b.x; v[5] = (f16)b.y; v[6] = (f16)b.z; v[7] = (f16)b.w;
          *(f16x8*)(xs + row * 32 + 16) = v;
        }
      }
      __syncthreads();
      const f16* hph = h1b + (size_t)((d + 1) & 1) * 262144;
      const f16* hpl = hph + 131072;
      f16* hoh = h1b + (size_t)(d & 1) * 262144;
      f16* hol = hoh + 131072;
      f32x4 aR = {0,0,0,0}, aZ = {0,0,0,0}, aN = {0,0,0,0}, aNx = {0,0,0,0};
      gemmK1024(hph, hpl, Wsh, lane, wv, aR, aZ, aN);
      gemmX(xs, wih_s, lane, wv, aR, aZ, aNx);
      gru_epilogue(aR, aZ, aN, aNx, bR, bZ, bIN, bHN, hph, hpl, hoh, hol, u, b0);
    }
    gbar(flags, rel, ph++);
    if (role == 3) {
      const f16* hd = h1b + (size_t)(d & 1) * 262144;
      fc_step(hd, hd + 131072, fcW_s, fcbv, bid - 192, tid,
              out + (size_t)(d + 1) * 1024, pbuf + (size_t)(d & 1) * 1024);
    }
    gbar(flags, rel, ph++);
  }
}

// ------------------------------------ host -----------------------------------
extern "C" void kernel_launch(void* const* d_in, const int* in_sizes, int n_in,
                              void* d_out, int out_size, void* d_ws, size_t ws_size,
                              hipStream_t stream) {
  (void)in_sizes; (void)n_in; (void)out_size; (void)ws_size;
  gru_persist<<<NB, NT, 0, stream>>>(
      (const float*)d_in[0], (const float*)d_in[1],
      (const float*)d_in[4], (const float*)d_in[5],
      (const float*)d_in[6], (const float*)d_in[7],
      (const float*)d_in[8], (const float*)d_in[9],
      (const float*)d_in[10], (const float*)d_in[11],
      (const float*)d_in[12], (const float*)d_in[13],
      (const float*)d_in[14], (const float*)d_in[15],
      (const float*)d_in[16], (const float*)d_in[17],
      (float*)d_out, (char*)d_ws);
}

// Round 5
// 11981.532 us; speedup vs baseline: 3.9160x; 1.2265x over previous
//
#include <hip/hip_runtime.h>
#include <cstdint>
#include <cstddef>

// GRU_56607668961499: B=128, T=512, PRED=24, F=16, L=8, H=1024
// R5: persistent kernel (R4 dataflow, proven correct) + per-XCD-leader barrier:
// R4 executed 208 buffer_wbl2 + 208 buffer_inv per tick (each a full L2
// tag-walk, ~26 serialized per XCD) -> ~25us/barrier. One wbl2+inv per XCD
// (leader elected via HW_REG_XCC_ID) is sufficient: blocks drain vmcnt at
// __syncthreads before raising arrival flags (stores complete in shared L2),
// leader's wbl2 flushes them all; leader's inv clears stale clean lines for
// the whole XCD. L1 staleness impossible by capacity (>=256KB contiguous
// streamed through 32KB L1 per tick). Poll loads are sc1 (bypass L2) so they
// cannot repopulate stale lines during the inv window.

typedef _Float16 f16;
typedef f16 f16x8 __attribute__((ext_vector_type(8)));
typedef float f32x4 __attribute__((ext_vector_type(4)));

#define NB 208
#define NT 512
#define H_ 1024

__device__ __forceinline__ float sigm(float x) { return 1.0f / (1.0f + __expf(-x)); }

// ---------------- init barrier (R4 style, per-block fences — proven) ---------
__device__ __forceinline__ void gbar(int* flags, int* rel, int phase) {
  __syncthreads();
  const int tid = threadIdx.x;
  if (blockIdx.x == 0) {
    if (tid == 0) {
      __builtin_amdgcn_fence(__ATOMIC_RELEASE, "agent");
      __hip_atomic_store(&flags[0], phase, __ATOMIC_RELAXED, __HIP_MEMORY_SCOPE_AGENT);
    }
    if (tid < NB) {
      while (__hip_atomic_load(&flags[tid], __ATOMIC_RELAXED, __HIP_MEMORY_SCOPE_AGENT) < phase)
        __builtin_amdgcn_s_sleep(1);
    }
    __syncthreads();
    if (tid == 0) {
      __hip_atomic_store(rel, phase, __ATOMIC_RELAXED, __HIP_MEMORY_SCOPE_AGENT);
      __builtin_amdgcn_fence(__ATOMIC_ACQUIRE, "agent");
    }
  } else {
    if (tid == 0) {
      __builtin_amdgcn_fence(__ATOMIC_RELEASE, "agent");
      __hip_atomic_store(&flags[blockIdx.x], phase, __ATOMIC_RELAXED, __HIP_MEMORY_SCOPE_AGENT);
      while (__hip_atomic_load(rel, __ATOMIC_RELAXED, __HIP_MEMORY_SCOPE_AGENT) < phase)
        __builtin_amdgcn_s_sleep(1);
      __builtin_amdgcn_fence(__ATOMIC_ACQUIRE, "agent");
    }
  }
  __syncthreads();
}

// ---------------- fast barrier: one wbl2+inv per XCD (leader) ----------------
__device__ __forceinline__ void fastbar(int* flags2, int* done, int fph, int nl,
                                        bool lead) {
  __syncthreads();   // drains each wave's vmcnt -> all stores complete in L2
  const int tid = threadIdx.x;
  if (tid == 0)
    __hip_atomic_store(&flags2[blockIdx.x], fph, __ATOMIC_RELAXED, __HIP_MEMORY_SCOPE_AGENT);
  if (lead) {
    if (tid < NB) {
      while (__hip_atomic_load(&flags2[tid], __ATOMIC_RELAXED, __HIP_MEMORY_SCOPE_AGENT) < fph)
        __builtin_amdgcn_s_sleep(1);
    }
    __syncthreads();
    if (tid == 0) {
      // release: wbl2 flushes THIS XCD's dirty lines (all blocks' stores are
      // already in L2); acquire: inv clears stale clean lines for the XCD.
      __builtin_amdgcn_fence(__ATOMIC_ACQ_REL, "agent");
      __hip_atomic_fetch_add(done, 1, __ATOMIC_RELAXED, __HIP_MEMORY_SCOPE_AGENT);
    }
  }
  if (tid == 0) {
    const int tgt = fph * nl;
    while (__hip_atomic_load(done, __ATOMIC_RELAXED, __HIP_MEMORY_SCOPE_AGENT) < tgt)
      __builtin_amdgcn_s_sleep(1);
  }
  __syncthreads();
}

// ------------- stage 48 rows x 1024 K of fp32 weights -> fp16 LDS, swizzled --
__device__ __forceinline__ void stage_W48(const float* __restrict__ W, int Ubase,
                                          f16* Wsh, int tid) {
  for (int i = tid; i < 6144; i += NT) {
    int row = i >> 7;      // 0..47  ([gate][unit])
    int k8 = i & 127;
    const float* src = W + ((size_t)((row >> 4) << 10) + Ubase + (row & 15)) * H_ + (k8 << 3);
    float4 a = *(const float4*)(src);
    float4 b = *(const float4*)(src + 4);
    f16x8 v;
    v[0] = (f16)a.x; v[1] = (f16)a.y; v[2] = (f16)a.z; v[3] = (f16)a.w;
    v[4] = (f16)b.x; v[5] = (f16)b.y; v[6] = (f16)b.z; v[7] = (f16)b.w;
    *(f16x8*)(Wsh + ((row << 10) + ((k8 ^ (row & 7)) << 3))) = v;
  }
}

__device__ __forceinline__ void stage_wih(const float* __restrict__ W, int Ubase,
                                          f16* wih_s, int tid) {
  for (int i = tid; i < 48 * 32; i += NT) {
    int row = i >> 5, k = i & 31;
    float v = (k < 24) ? W[((size_t)((row >> 4) << 10) + Ubase + (row & 15)) * 24 + k] : 0.f;
    wih_s[row * 32 + k] = (f16)v;
  }
}

// ---------------- K=1024 3-gate GEMM, A = hi+lo fp16 planes ------------------
__device__ __forceinline__ void gemmK1024(const f16* __restrict__ Ahp,
                                          const f16* __restrict__ Alp,
                                          const f16* Wsh, int lane, int wv,
                                          f32x4& aR, f32x4& aZ, f32x4& aN) {
  const int q = lane >> 4, r = lane & 15;
  const f16* pa = Ahp + (size_t)(wv * 16 + r) * H_ + q * 8;
  const f16* pl = Alp + (size_t)(wv * 16 + r) * H_ + q * 8;
  const f16* w0 = Wsh + ((0 * 16 + r) << 10);
  const f16* w1 = Wsh + ((1 * 16 + r) << 10);
  const f16* w2 = Wsh + ((2 * 16 + r) << 10);
  const int sw = r & 7;
#pragma unroll 4
  for (int kt = 0; kt < 32; ++kt) {
    f16x8 Ah = *(const f16x8*)(pa + kt * 32);
    f16x8 Al = *(const f16x8*)(pl + kt * 32);
    int ko = (((kt * 4 + q) ^ sw) << 3);
    f16x8 B0 = *(const f16x8*)(w0 + ko);
    f16x8 B1 = *(const f16x8*)(w1 + ko);
    f16x8 B2 = *(const f16x8*)(w2 + ko);
    aR = __builtin_amdgcn_mfma_f32_16x16x32_f16(Ah, B0, aR, 0, 0, 0);
    aZ = __builtin_amdgcn_mfma_f32_16x16x32_f16(Ah, B1, aZ, 0, 0, 0);
    aN = __builtin_amdgcn_mfma_f32_16x16x32_f16(Ah, B2, aN, 0, 0, 0);
    aR = __builtin_amdgcn_mfma_f32_16x16x32_f16(Al, B0, aR, 0, 0, 0);
    aZ = __builtin_amdgcn_mfma_f32_16x16x32_f16(Al, B1, aZ, 0, 0, 0);
    aN = __builtin_amdgcn_mfma_f32_16x16x32_f16(Al, B2, aN, 0, 0, 0);
  }
}

// ---------------- x-side K=32 (padded 24) MFMA -------------------------------
__device__ __forceinline__ void gemmX(const f16* xs, const f16* wih_s, int lane, int wv,
                                      f32x4& aR, f32x4& aZ, f32x4& aNx) {
  const int q = lane >> 4, r = lane & 15;
  f16x8 Ax = *(const f16x8*)(xs + (wv * 16 + r) * 32 + q * 8);
  f16x8 B0 = *(const f16x8*)(wih_s + (0 * 16 + r) * 32 + q * 8);
  f16x8 B1 = *(const f16x8*)(wih_s + (1 * 16 + r) * 32 + q * 8);
  f16x8 B2 = *(const f16x8*)(wih_s + (2 * 16 + r) * 32 + q * 8);
  aR = __builtin_amdgcn_mfma_f32_16x16x32_f16(Ax, B0, aR, 0, 0, 0);
  aZ = __builtin_amdgcn_mfma_f32_16x16x32_f16(Ax, B1, aZ, 0, 0, 0);
  aNx = __builtin_amdgcn_mfma_f32_16x16x32_f16(Ax, B2, aNx, 0, 0, 0);
}

// ---------------- fused GRU nonlinearity + h store (hi/lo fp16) --------------
__device__ __forceinline__ void gru_epilogue(const f32x4& aR, const f32x4& aZ,
                                             const f32x4& aNh, const f32x4& aNx,
                                             float bR, float bZ, float bIN, float bHN,
                                             const f16* hph, const f16* hpl,
                                             f16* hoh, f16* hol, int u, int b0) {
#pragma unroll
  for (int i = 0; i < 4; ++i) {
    float rg = sigm(aR[i] + bR);
    float zg = sigm(aZ[i] + bZ);
    float ng = tanhf(aNx[i] + bIN + rg * (aNh[i] + bHN));
    size_t off = (size_t)(b0 + i) * H_ + u;
    float hp = (float)hph[off] + (float)hpl[off];
    float hn = (1.f - zg) * ng + zg * hp;
    f16 hh = (f16)hn;
    hoh[off] = hh;
    hol[off] = (f16)(hn - (float)hh);
  }
}

// ---------------- FC head: p = h @ fcW.T + fcb (16 blocks x 8 rows) ----------
__device__ __forceinline__ void fc_step(const f16* hh, const f16* hl,
                                        const float* fcW_s, float fcbv, int fcblk,
                                        int tid, float* out_slice, float* pdst) {
  int b_loc = tid >> 6;            // 0..7
  int l = (tid >> 3) & 7;
  int strip = tid & 7;             // lanes 0..7 within wave
  int b = fcblk * 8 + b_loc;
  const f16* ph = hh + (size_t)b * H_ + strip * 128;
  const f16* pl = hl + (size_t)b * H_ + strip * 128;
  const float* pw = fcW_s + l * H_ + strip * 128;
  float s = 0.f;
  for (int j = 0; j < 128; j += 8) {
    f16x8 a = *(const f16x8*)(ph + j);
    f16x8 c = *(const f16x8*)(pl + j);
#pragma unroll
    for (int e = 0; e < 8; ++e) s += ((float)a[e] + (float)c[e]) * pw[j + e];
  }
  s += __shfl_xor(s, 1);
  s += __shfl_xor(s, 2);
  s += __shfl_xor(s, 4);
  if (strip == 0) {
    float v = s + fcbv;
    out_slice[b * 8 + l] = v;
    pdst[b * 8 + l] = v;
  }
}

// ------------------------------- persistent kernel ---------------------------
__global__ __launch_bounds__(NT, 2) void gru_persist(
    const float* __restrict__ feats, const float* __restrict__ labels,
    const float* __restrict__ wih0, const float* __restrict__ whh0,
    const float* __restrict__ bih0, const float* __restrict__ bhh0,
    const float* __restrict__ wih1, const float* __restrict__ whh1,
    const float* __restrict__ bih1, const float* __restrict__ bhh1,
    const float* __restrict__ dwih, const float* __restrict__ dwhh,
    const float* __restrict__ dbih, const float* __restrict__ dbhh,
    const float* __restrict__ fcW, const float* __restrict__ fcb,
    float* __restrict__ out, char* ws) {
  int* flags = (int*)ws;                          // init-barrier flags
  int* flags2 = (int*)(ws + 2048);                // fast-barrier flags
  int* ctrl = (int*)(ws + 4096);                  // [0]=rel [1]=done [2..9]=xcd_rank [10]=nleaders
  f16* h0b = (f16*)(ws + 8192);                   // [par][plane][128][1024]
  f16* h1b = h0b + 2 * 2 * 128 * H_;
  float* gi = (float*)(ws + 8192 + 2097152);      // [par][3072][128] f32
  float* pbuf = (float*)(ws + 8192 + 2097152 + 3145728);  // [par][128*8]

  const int bid = blockIdx.x, tid = threadIdx.x;
  const int lane = tid & 63, wv = tid >> 6;
  const int q = lane >> 4, r = lane & 15;
  const int role = bid >> 6;                      // 0:L0 1:L1i 2:L1h 3:FC
  const int Ubase = (bid & 63) << 4;
  const int u = Ubase + r;
  const int b0 = wv * 16 + q * 4;

  __shared__ __align__(16) unsigned char smem[109568];
  __shared__ int s_lead, s_nl;
  f16* Wsh = (f16*)smem;                          // 48 x 1024 fp16 (96 KB)
  f16* xs = (f16*)(smem + 98304);                 // 128 x 32 fp16
  f16* wih_s = (f16*)(smem + 106496);             // 48 x 32 fp16
  float* fcW_s = (float*)smem;                    // role 3: 8 x 1024 f32

  // zero control vars (done, xcd_rank[8], nleaders) — visible after gbar(1)
  if (bid == 0 && tid >= 1 && tid <= 10) ctrl[tid] = 0;

  // zero h state (2 MB contiguous)
  {
    uint32_t* zp = (uint32_t*)h0b;
    for (int i = bid * NT + tid; i < 524288; i += NB * NT) zp[i] = 0;
  }
  for (int i = tid; i < 2048; i += NT) ((uint32_t*)xs)[i] = 0;

  // stage persistent weights
  if (role == 0) { stage_W48(whh0, Ubase, Wsh, tid); stage_wih(wih0, Ubase, wih_s, tid); }
  else if (role == 1) stage_W48(wih1, Ubase, Wsh, tid);
  else if (role == 2) stage_W48(whh1, Ubase, Wsh, tid);
  else for (int i = tid; i < 8192; i += NT) fcW_s[i] = fcW[i];

  float bR = 0.f, bZ = 0.f, bIN = 0.f, bHN = 0.f;
  if (role == 0) {
    bR = bih0[u] + bhh0[u]; bZ = bih0[1024 + u] + bhh0[1024 + u];
    bIN = bih0[2048 + u];   bHN = bhh0[2048 + u];
  } else if (role == 2) {
    bR = bih1[u] + bhh1[u]; bZ = bih1[1024 + u] + bhh1[1024 + u];
    bIN = bih1[2048 + u];   bHN = bhh1[2048 + u];
  }
  float fcbv = (role == 3) ? fcb[(tid >> 3) & 7] : 0.f;

  gbar(flags, &ctrl[0], 1);   // ctrl zeroed + h zeroed visible

  // leader election by PHYSICAL XCD (correct under any block->XCD mapping)
  if (tid == 0) {
    int xcd;
    asm volatile("s_getreg_b32 %0, hwreg(HW_REG_XCC_ID)" : "=s"(xcd));
    int old = __hip_atomic_fetch_add(&ctrl[2 + (xcd & 7)], 1, __ATOMIC_RELAXED,
                                     __HIP_MEMORY_SCOPE_AGENT);
    int ld = (old == 0) ? 1 : 0;
    if (ld) __hip_atomic_fetch_add(&ctrl[10], 1, __ATOMIC_RELAXED, __HIP_MEMORY_SCOPE_AGENT);
    s_lead = ld;
  }
  gbar(flags, &ctrl[0], 2);   // elections visible
  if (tid == 0) s_nl = __hip_atomic_load(&ctrl[10], __ATOMIC_RELAXED, __HIP_MEMORY_SCOPE_AGENT);
  __syncthreads();
  const bool lead = (s_lead != 0);
  const int NL = s_nl;
  int fp = 0;

  // =================== encoder: 514 pipelined super-ticks ====================
  for (int s = 0; s < 514; ++s) {
    if (role == 0 && s < 512) {
      {
        int row = tid >> 2, k8 = tid & 3;
        if (k8 < 2) {
          const float* fpt = feats + ((size_t)row * 535 + s) * 16 + k8 * 8;
          float4 a = *(const float4*)fpt; float4 b = *(const float4*)(fpt + 4);
          f16x8 v;
          v[0] = (f16)a.x; v[1] = (f16)a.y; v[2] = (f16)a.z; v[3] = (f16)a.w;
          v[4] = (f16)b.x; v[5] = (f16)b.y; v[6] = (f16)b.z; v[7] = (f16)b.w;
          *(f16x8*)(xs + row * 32 + k8 * 8) = v;
        } else if (k8 == 2) {
          const float* lp = labels + ((size_t)row * 512 + s) * 8;
          float4 a = *(const float4*)lp; float4 b = *(const float4*)(lp + 4);
          f16x8 v;
          v[0] = (f16)a.x; v[1] = (f16)a.y; v[2] = (f16)a.z; v[3] = (f16)a.w;
          v[4] = (f16)b.x; v[5] = (f16)b.y; v[6] = (f16)b.z; v[7] = (f16)b.w;
          *(f16x8*)(xs + row * 32 + 16) = v;
        }
      }
      __syncthreads();
      const f16* hph = h0b + (size_t)((s + 1) & 1) * 262144;
      const f16* hpl = hph + 131072;
      f16* hoh = h0b + (size_t)(s & 1) * 262144;
      f16* hol = hoh + 131072;
      f32x4 aR = {0,0,0,0}, aZ = {0,0,0,0}, aN = {0,0,0,0}, aNx = {0,0,0,0};
      gemmK1024(hph, hpl, Wsh, lane, wv, aR, aZ, aN);
      gemmX(xs, wih_s, lane, wv, aR, aZ, aNx);
      gru_epilogue(aR, aZ, aN, aNx, bR, bZ, bIN, bHN, hph, hpl, hoh, hol, u, b0);
    } else if (role == 1 && s >= 1 && s <= 512) {
      const f16* hph = h0b + (size_t)((s - 1) & 1) * 262144;
      const f16* hpl = hph + 131072;
      f32x4 aR = {0,0,0,0}, aZ = {0,0,0,0}, aN = {0,0,0,0};
      gemmK1024(hph, hpl, Wsh, lane, wv, aR, aZ, aN);
      float* dst = gi + (size_t)((s - 1) & 1) * 393216;
      *(f32x4*)(dst + (size_t)u * 128 + b0) = aR;
      *(f32x4*)(dst + (size_t)(1024 + u) * 128 + b0) = aZ;
      *(f32x4*)(dst + (size_t)(2048 + u) * 128 + b0) = aN;
    } else if (role == 2 && s >= 2) {
      const f16* hph = h1b + (size_t)((s - 1) & 1) * 262144;
      const f16* hpl = hph + 131072;
      f16* hoh = h1b + (size_t)(s & 1) * 262144;
      f16* hol = hoh + 131072;
      f32x4 aR = {0,0,0,0}, aZ = {0,0,0,0}, aN = {0,0,0,0};
      gemmK1024(hph, hpl, Wsh, lane, wv, aR, aZ, aN);
      const float* gp = gi + (size_t)(s & 1) * 393216;
      f32x4 gR = *(const f32x4*)(gp + (size_t)u * 128 + b0);
      f32x4 gZ = *(const f32x4*)(gp + (size_t)(1024 + u) * 128 + b0);
      f32x4 gN = *(const f32x4*)(gp + (size_t)(2048 + u) * 128 + b0);
      f32x4 tR = aR + gR, tZ = aZ + gZ;
      gru_epilogue(tR, tZ, aN, gN, bR, bZ, bIN, bHN, hph, hpl, hoh, hol, u, b0);
    }
    fastbar(flags2, &ctrl[1], ++fp, NL, lead);
  }

  // =================== decoder prologue: ps + weight swap ====================
  if (role == 3) {
    const f16* hf = h1b + 262144;  // h1[511] in parity 1
    fc_step(hf, hf + 131072, fcW_s, fcbv, bid - 192, tid, out, pbuf + 1024);
  }
  if (role == 0) {
    stage_W48(dwhh, Ubase, Wsh, tid);
    stage_wih(dwih, Ubase, wih_s, tid);
    bR = dbih[u] + dbhh[u]; bZ = dbih[1024 + u] + dbhh[1024 + u];
    bIN = dbih[2048 + u];   bHN = dbhh[2048 + u];
  }
  fastbar(flags2, &ctrl[1], ++fp, NL, lead);

  // =================== decoder: 23 free-running ticks ========================
  for (int d = 0; d < 23; ++d) {
    if (role == 0) {
      {
        int row = tid >> 2, k8 = tid & 3;
        if (k8 < 2) {
          const float* fpt = feats + ((size_t)row * 535 + 512 + d) * 16 + k8 * 8;
          float4 a = *(const float4*)fpt; float4 b = *(const float4*)(fpt + 4);
          f16x8 v;
          v[0] = (f16)a.x; v[1] = (f16)a.y; v[2] = (f16)a.z; v[3] = (f16)a.w;
          v[4] = (f16)b.x; v[5] = (f16)b.y; v[6] = (f16)b.z; v[7] = (f16)b.w;
          *(f16x8*)(xs + row * 32 + k8 * 8) = v;
        } else if (k8 == 2) {
          const float* pp = pbuf + (size_t)((d + 1) & 1) * 1024 + row * 8;
          float4 a = *(const float4*)pp; float4 b = *(const float4*)(pp + 4);
          f16x8 v;
          v[0] = (f16)a.x; v[1] = (f16)a.y; v[2] = (f16)a.z; v[3] = (f16)a.w;
          v[4] = (f16)b.x; v[5] = (f16)b.y; v[6] = (f16)b.z; v[7] = (f16)b.w;
          *(f16x8*)(xs + row * 32 + 16) = v;
        }
      }
      __syncthreads();
      const f16* hph = h1b + (size_t)((d + 1) & 1) * 262144;
      const f16* hpl = hph + 131072;
      f16* hoh = h1b + (size_t)(d & 1) * 262144;
      f16* hol = hoh + 131072;
      f32x4 aR = {0,0,0,0}, aZ = {0,0,0,0}, aN = {0,0,0,0}, aNx = {0,0,0,0};
      gemmK1024(hph, hpl, Wsh, lane, wv, aR, aZ, aN);
      gemmX(xs, wih_s, lane, wv, aR, aZ, aNx);
      gru_epilogue(aR, aZ, aN, aNx, bR, bZ, bIN, bHN, hph, hpl, hoh, hol, u, b0);
    }
    fastbar(flags2, &ctrl[1], ++fp, NL, lead);
    if (role == 3) {
      const f16* hd = h1b + (size_t)(d & 1) * 262144;
      fc_step(hd, hd + 131072, fcW_s, fcbv, bid - 192, tid,
              out + (size_t)(d + 1) * 1024, pbuf + (size_t)(d & 1) * 1024);
    }
    fastbar(flags2, &ctrl[1], ++fp, NL, lead);
  }
}

// ------------------------------------ host -----------------------------------
extern "C" void kernel_launch(void* const* d_in, const int* in_sizes, int n_in,
                              void* d_out, int out_size, void* d_ws, size_t ws_size,
                              hipStream_t stream) {
  (void)in_sizes; (void)n_in; (void)out_size; (void)ws_size;
  gru_persist<<<NB, NT, 0, stream>>>(
      (const float*)d_in[0], (const float*)d_in[1],
      (const float*)d_in[4], (const float*)d_in[5],
      (const float*)d_in[6], (const float*)d_in[7],
      (const float*)d_in[8], (const float*)d_in[9],
      (const float*)d_in[10], (const float*)d_in[11],
      (const float*)d_in[12], (const float*)d_in[13],
      (const float*)d_in[14], (const float*)d_in[15],
      (const float*)d_in[16], (const float*)d_in[17],
      (float*)d_out, (char*)d_ws);
}

// Round 6
// 11494.924 us; speedup vs baseline: 4.0818x; 1.0423x over previous
//
#include <hip/hip_runtime.h>
#include <cstdint>
#include <cstddef>

// GRU_56607668961499: B=128, T=512, PRED=24, F=16, L=8, H=1024
// R6: persistent kernel + RING-BUFFERED state (8 slots for h0/h1/gi/p):
// each tick writes a FRESH slot, so consumer L2s have never cached those
// addresses -> plain cached loads are fresh with NO per-tick invalidate.
// buffer_inv only every 4th barrier (ring-recycling guarantee: slot reuse
// distance is 8+ phases -> >=2 invs in every reuse window). Producer publish
// unchanged from R5 (proven): plain stores drain into XCD L2 at syncthreads,
// per-XCD leader fence(RELEASE)=wbl2 flushes them to L3, done-counter gates
// all consumers behind every XCD's flush. R5's ~21us/tick was the per-tick
// inv (cold L2 refill cascade, 4.3MB/tick at ~900cyc L3 latency) -- removed.

typedef _Float16 f16;
typedef f16 f16x8 __attribute__((ext_vector_type(8)));
typedef float f32x4 __attribute__((ext_vector_type(4)));

#define NB 208
#define NT 512
#define H_ 1024
#define HSLOT 262144       // f16 per h ring slot ([plane][128][1024])
#define GSLOT 393216       // f32 per gi ring slot ([3072][128])

__device__ __forceinline__ float sigm(float x) { return 1.0f / (1.0f + __expf(-x)); }

// ---------------- init barrier (R4 style, per-block fences — proven) ---------
__device__ __forceinline__ void gbar(int* flags, int* rel, int phase) {
  __syncthreads();
  const int tid = threadIdx.x;
  if (blockIdx.x == 0) {
    if (tid == 0) {
      __builtin_amdgcn_fence(__ATOMIC_RELEASE, "agent");
      __hip_atomic_store(&flags[0], phase, __ATOMIC_RELAXED, __HIP_MEMORY_SCOPE_AGENT);
    }
    if (tid < NB) {
      while (__hip_atomic_load(&flags[tid], __ATOMIC_RELAXED, __HIP_MEMORY_SCOPE_AGENT) < phase)
        __builtin_amdgcn_s_sleep(1);
    }
    __syncthreads();
    if (tid == 0) {
      __hip_atomic_store(rel, phase, __ATOMIC_RELAXED, __HIP_MEMORY_SCOPE_AGENT);
      __builtin_amdgcn_fence(__ATOMIC_ACQUIRE, "agent");
    }
  } else {
    if (tid == 0) {
      __builtin_amdgcn_fence(__ATOMIC_RELEASE, "agent");
      __hip_atomic_store(&flags[blockIdx.x], phase, __ATOMIC_RELAXED, __HIP_MEMORY_SCOPE_AGENT);
      while (__hip_atomic_load(rel, __ATOMIC_RELAXED, __HIP_MEMORY_SCOPE_AGENT) < phase)
        __builtin_amdgcn_s_sleep(1);
      __builtin_amdgcn_fence(__ATOMIC_ACQUIRE, "agent");
    }
  }
  __syncthreads();
}

// ------- fast barrier: leader wbl2 each tick; inv only when do_inv ----------
__device__ __forceinline__ void fastbar(int* flags2, int* done, int fph, int nl,
                                        bool lead) {
  __syncthreads();   // drains each wave's vmcnt -> all stores complete in L2
  const int tid = threadIdx.x;
  if (tid == 0)
    __hip_atomic_store(&flags2[blockIdx.x], fph, __ATOMIC_RELAXED, __HIP_MEMORY_SCOPE_AGENT);
  if (lead) {
    if (tid < NB) {
      while (__hip_atomic_load(&flags2[tid], __ATOMIC_RELAXED, __HIP_MEMORY_SCOPE_AGENT) < fph)
        __builtin_amdgcn_s_sleep(1);
    }
    __syncthreads();
    if (tid == 0) {
      // publish this XCD's dirty lines to the coherence point (wbl2)
      __builtin_amdgcn_fence(__ATOMIC_RELEASE, "agent");
      // ring-recycle inv: only every 4th phase (reuse distance >= 8 phases)
      if ((fph & 3) == 0)
        __builtin_amdgcn_fence(__ATOMIC_ACQUIRE, "agent");
      __hip_atomic_fetch_add(done, 1, __ATOMIC_RELAXED, __HIP_MEMORY_SCOPE_AGENT);
    }
  }
  if (tid == 0) {
    const int tgt = fph * nl;
    while (__hip_atomic_load(done, __ATOMIC_RELAXED, __HIP_MEMORY_SCOPE_AGENT) < tgt)
      __builtin_amdgcn_s_sleep(1);
  }
  __syncthreads();
}

// ------------- stage 48 rows x 1024 K of fp32 weights -> fp16 LDS, swizzled --
__device__ __forceinline__ void stage_W48(const float* __restrict__ W, int Ubase,
                                          f16* Wsh, int tid) {
  for (int i = tid; i < 6144; i += NT) {
    int row = i >> 7;      // 0..47  ([gate][unit])
    int k8 = i & 127;
    const float* src = W + ((size_t)((row >> 4) << 10) + Ubase + (row & 15)) * H_ + (k8 << 3);
    float4 a = *(const float4*)(src);
    float4 b = *(const float4*)(src + 4);
    f16x8 v;
    v[0] = (f16)a.x; v[1] = (f16)a.y; v[2] = (f16)a.z; v[3] = (f16)a.w;
    v[4] = (f16)b.x; v[5] = (f16)b.y; v[6] = (f16)b.z; v[7] = (f16)b.w;
    *(f16x8*)(Wsh + ((row << 10) + ((k8 ^ (row & 7)) << 3))) = v;
  }
}

__device__ __forceinline__ void stage_wih(const float* __restrict__ W, int Ubase,
                                          f16* wih_s, int tid) {
  for (int i = tid; i < 48 * 32; i += NT) {
    int row = i >> 5, k = i & 31;
    float v = (k < 24) ? W[((size_t)((row >> 4) << 10) + Ubase + (row & 15)) * 24 + k] : 0.f;
    wih_s[row * 32 + k] = (f16)v;
  }
}

// ---------------- K=1024 3-gate GEMM, A = hi+lo fp16 planes ------------------
__device__ __forceinline__ void gemmK1024(const f16* __restrict__ Ahp,
                                          const f16* __restrict__ Alp,
                                          const f16* Wsh, int lane, int wv,
                                          f32x4& aR, f32x4& aZ, f32x4& aN) {
  const int q = lane >> 4, r = lane & 15;
  const f16* pa = Ahp + (size_t)(wv * 16 + r) * H_ + q * 8;
  const f16* pl = Alp + (size_t)(wv * 16 + r) * H_ + q * 8;
  const f16* w0 = Wsh + ((0 * 16 + r) << 10);
  const f16* w1 = Wsh + ((1 * 16 + r) << 10);
  const f16* w2 = Wsh + ((2 * 16 + r) << 10);
  const int sw = r & 7;
#pragma unroll 4
  for (int kt = 0; kt < 32; ++kt) {
    f16x8 Ah = *(const f16x8*)(pa + kt * 32);
    f16x8 Al = *(const f16x8*)(pl + kt * 32);
    int ko = (((kt * 4 + q) ^ sw) << 3);
    f16x8 B0 = *(const f16x8*)(w0 + ko);
    f16x8 B1 = *(const f16x8*)(w1 + ko);
    f16x8 B2 = *(const f16x8*)(w2 + ko);
    aR = __builtin_amdgcn_mfma_f32_16x16x32_f16(Ah, B0, aR, 0, 0, 0);
    aZ = __builtin_amdgcn_mfma_f32_16x16x32_f16(Ah, B1, aZ, 0, 0, 0);
    aN = __builtin_amdgcn_mfma_f32_16x16x32_f16(Ah, B2, aN, 0, 0, 0);
    aR = __builtin_amdgcn_mfma_f32_16x16x32_f16(Al, B0, aR, 0, 0, 0);
    aZ = __builtin_amdgcn_mfma_f32_16x16x32_f16(Al, B1, aZ, 0, 0, 0);
    aN = __builtin_amdgcn_mfma_f32_16x16x32_f16(Al, B2, aN, 0, 0, 0);
  }
}

// ---------------- x-side K=32 (padded 24) MFMA -------------------------------
__device__ __forceinline__ void gemmX(const f16* xs, const f16* wih_s, int lane, int wv,
                                      f32x4& aR, f32x4& aZ, f32x4& aNx) {
  const int q = lane >> 4, r = lane & 15;
  f16x8 Ax = *(const f16x8*)(xs + (wv * 16 + r) * 32 + q * 8);
  f16x8 B0 = *(const f16x8*)(wih_s + (0 * 16 + r) * 32 + q * 8);
  f16x8 B1 = *(const f16x8*)(wih_s + (1 * 16 + r) * 32 + q * 8);
  f16x8 B2 = *(const f16x8*)(wih_s + (2 * 16 + r) * 32 + q * 8);
  aR = __builtin_amdgcn_mfma_f32_16x16x32_f16(Ax, B0, aR, 0, 0, 0);
  aZ = __builtin_amdgcn_mfma_f32_16x16x32_f16(Ax, B1, aZ, 0, 0, 0);
  aNx = __builtin_amdgcn_mfma_f32_16x16x32_f16(Ax, B2, aNx, 0, 0, 0);
}

// ---------------- fused GRU nonlinearity + h store (hi/lo fp16) --------------
__device__ __forceinline__ void gru_epilogue(const f32x4& aR, const f32x4& aZ,
                                             const f32x4& aNh, const f32x4& aNx,
                                             float bR, float bZ, float bIN, float bHN,
                                             const f16* hph, const f16* hpl,
                                             f16* hoh, f16* hol, int u, int b0) {
#pragma unroll
  for (int i = 0; i < 4; ++i) {
    float rg = sigm(aR[i] + bR);
    float zg = sigm(aZ[i] + bZ);
    float ng = tanhf(aNx[i] + bIN + rg * (aNh[i] + bHN));
    size_t off = (size_t)(b0 + i) * H_ + u;
    float hp = (float)hph[off] + (float)hpl[off];
    float hn = (1.f - zg) * ng + zg * hp;
    f16 hh = (f16)hn;
    hoh[off] = hh;
    hol[off] = (f16)(hn - (float)hh);
  }
}

// ---------------- FC head: p = h @ fcW.T + fcb (16 blocks x 8 rows) ----------
__device__ __forceinline__ void fc_step(const f16* hh, const f16* hl,
                                        const float* fcW_s, float fcbv, int fcblk,
                                        int tid, float* out_slice, float* pdst) {
  int b_loc = tid >> 6;            // 0..7
  int l = (tid >> 3) & 7;
  int strip = tid & 7;             // lanes 0..7 within wave
  int b = fcblk * 8 + b_loc;
  const f16* ph = hh + (size_t)b * H_ + strip * 128;
  const f16* pl = hl + (size_t)b * H_ + strip * 128;
  const float* pw = fcW_s + l * H_ + strip * 128;
  float s = 0.f;
  for (int j = 0; j < 128; j += 8) {
    f16x8 a = *(const f16x8*)(ph + j);
    f16x8 c = *(const f16x8*)(pl + j);
#pragma unroll
    for (int e = 0; e < 8; ++e) s += ((float)a[e] + (float)c[e]) * pw[j + e];
  }
  s += __shfl_xor(s, 1);
  s += __shfl_xor(s, 2);
  s += __shfl_xor(s, 4);
  if (strip == 0) {
    float v = s + fcbv;
    out_slice[b * 8 + l] = v;
    pdst[b * 8 + l] = v;
  }
}

// ------------------------------- persistent kernel ---------------------------
__global__ __launch_bounds__(NT, 2) void gru_persist(
    const float* __restrict__ feats, const float* __restrict__ labels,
    const float* __restrict__ wih0, const float* __restrict__ whh0,
    const float* __restrict__ bih0, const float* __restrict__ bhh0,
    const float* __restrict__ wih1, const float* __restrict__ whh1,
    const float* __restrict__ bih1, const float* __restrict__ bhh1,
    const float* __restrict__ dwih, const float* __restrict__ dwhh,
    const float* __restrict__ dbih, const float* __restrict__ dbhh,
    const float* __restrict__ fcW, const float* __restrict__ fcb,
    float* __restrict__ out, char* ws) {
  int* flags = (int*)ws;                          // init-barrier flags
  int* flags2 = (int*)(ws + 2048);                // fast-barrier flags
  int* ctrl = (int*)(ws + 4096);                  // [0]=rel [1]=done [2..9]=xcd_rank [10]=nleaders
  f16* h0r = (f16*)(ws + 8192);                   // 8 slots x [plane][128][1024]
  f16* h1r = (f16*)(ws + 8192 + 4194304);         // 8 slots (also decoder h)
  float* gir = (float*)(ws + 8192 + 8388608);     // 8 slots x [3072][128] f32
  float* pbr = (float*)(ws + 8192 + 8388608 + 12582912);  // 8 slots x 1024 f32

  const int bid = blockIdx.x, tid = threadIdx.x;
  const int lane = tid & 63, wv = tid >> 6;
  const int q = lane >> 4, r = lane & 15;
  const int role = bid >> 6;                      // 0:L0 1:L1i 2:L1h 3:FC
  const int Ubase = (bid & 63) << 4;
  const int u = Ubase + r;
  const int b0 = wv * 16 + q * 4;

  __shared__ __align__(16) unsigned char smem[109568];
  __shared__ int s_lead, s_nl;
  f16* Wsh = (f16*)smem;                          // 48 x 1024 fp16 (96 KB)
  f16* xs = (f16*)(smem + 98304);                 // 128 x 32 fp16
  f16* wih_s = (f16*)(smem + 106496);             // 48 x 32 fp16
  float* fcW_s = (float*)smem;                    // role 3: 8 x 1024 f32

  // zero control vars
  if (bid == 0 && tid >= 1 && tid <= 10) ctrl[tid] = 0;

  // zero initial h slots (slot 7 of both rings)
  {
    uint32_t* z0 = (uint32_t*)(h0r + 7 * HSLOT);
    uint32_t* z1 = (uint32_t*)(h1r + 7 * HSLOT);
    for (int i = bid * NT + tid; i < 131072; i += NB * NT) { z0[i] = 0; z1[i] = 0; }
  }
  for (int i = tid; i < 2048; i += NT) ((uint32_t*)xs)[i] = 0;

  // stage persistent weights
  if (role == 0) { stage_W48(whh0, Ubase, Wsh, tid); stage_wih(wih0, Ubase, wih_s, tid); }
  else if (role == 1) stage_W48(wih1, Ubase, Wsh, tid);
  else if (role == 2) stage_W48(whh1, Ubase, Wsh, tid);
  else for (int i = tid; i < 8192; i += NT) fcW_s[i] = fcW[i];

  float bR = 0.f, bZ = 0.f, bIN = 0.f, bHN = 0.f;
  if (role == 0) {
    bR = bih0[u] + bhh0[u]; bZ = bih0[1024 + u] + bhh0[1024 + u];
    bIN = bih0[2048 + u];   bHN = bhh0[2048 + u];
  } else if (role == 2) {
    bR = bih1[u] + bhh1[u]; bZ = bih1[1024 + u] + bhh1[1024 + u];
    bIN = bih1[2048 + u];   bHN = bhh1[2048 + u];
  }
  float fcbv = (role == 3) ? fcb[(tid >> 3) & 7] : 0.f;

  gbar(flags, &ctrl[0], 1);   // ctrl + zeroed slots visible

  // leader election by PHYSICAL XCD
  if (tid == 0) {
    int xcd;
    asm volatile("s_getreg_b32 %0, hwreg(HW_REG_XCC_ID)" : "=s"(xcd));
    int old = __hip_atomic_fetch_add(&ctrl[2 + (xcd & 7)], 1, __ATOMIC_RELAXED,
                                     __HIP_MEMORY_SCOPE_AGENT);
    int ld = (old == 0) ? 1 : 0;
    if (ld) __hip_atomic_fetch_add(&ctrl[10], 1, __ATOMIC_RELAXED, __HIP_MEMORY_SCOPE_AGENT);
    s_lead = ld;
  }
  gbar(flags, &ctrl[0], 2);   // elections visible
  if (tid == 0) s_nl = __hip_atomic_load(&ctrl[10], __ATOMIC_RELAXED, __HIP_MEMORY_SCOPE_AGENT);
  __syncthreads();
  const bool lead = (s_lead != 0);
  const int NL = s_nl;
  int fp = 0;

  // =================== encoder: 514 pipelined super-ticks ====================
  for (int s = 0; s < 514; ++s) {
    if (role == 0 && s < 512) {
      {
        int row = tid >> 2, k8 = tid & 3;
        if (k8 < 2) {
          const float* fpt = feats + ((size_t)row * 535 + s) * 16 + k8 * 8;
          float4 a = *(const float4*)fpt; float4 b = *(const float4*)(fpt + 4);
          f16x8 v;
          v[0] = (f16)a.x; v[1] = (f16)a.y; v[2] = (f16)a.z; v[3] = (f16)a.w;
          v[4] = (f16)b.x; v[5] = (f16)b.y; v[6] = (f16)b.z; v[7] = (f16)b.w;
          *(f16x8*)(xs + row * 32 + k8 * 8) = v;
        } else if (k8 == 2) {
          const float* lp = labels + ((size_t)row * 512 + s) * 8;
          float4 a = *(const float4*)lp; float4 b = *(const float4*)(lp + 4);
          f16x8 v;
          v[0] = (f16)a.x; v[1] = (f16)a.y; v[2] = (f16)a.z; v[3] = (f16)a.w;
          v[4] = (f16)b.x; v[5] = (f16)b.y; v[6] = (f16)b.z; v[7] = (f16)b.w;
          *(f16x8*)(xs + row * 32 + 16) = v;
        }
      }
      __syncthreads();
      const f16* hph = h0r + (size_t)((s + 7) & 7) * HSLOT;  // h0[s-1]
      const f16* hpl = hph + 131072;
      f16* hoh = h0r + (size_t)(s & 7) * HSLOT;              // h0[s]
      f16* hol = hoh + 131072;
      f32x4 aR = {0,0,0,0}, aZ = {0,0,0,0}, aN = {0,0,0,0}, aNx = {0,0,0,0};
      gemmK1024(hph, hpl, Wsh, lane, wv, aR, aZ, aN);
      gemmX(xs, wih_s, lane, wv, aR, aZ, aNx);
      gru_epilogue(aR, aZ, aN, aNx, bR, bZ, bIN, bHN, hph, hpl, hoh, hol, u, b0);
    } else if (role == 1 && s >= 1 && s <= 512) {
      const f16* hph = h0r + (size_t)((s + 7) & 7) * HSLOT;  // h0[s-1]
      const f16* hpl = hph + 131072;
      f32x4 aR = {0,0,0,0}, aZ = {0,0,0,0}, aN = {0,0,0,0};
      gemmK1024(hph, hpl, Wsh, lane, wv, aR, aZ, aN);
      float* dst = gir + (size_t)((s + 7) & 7) * GSLOT;      // gi for h0[s-1]
      *(f32x4*)(dst + (size_t)u * 128 + b0) = aR;
      *(f32x4*)(dst + (size_t)(1024 + u) * 128 + b0) = aZ;
      *(f32x4*)(dst + (size_t)(2048 + u) * 128 + b0) = aN;
    } else if (role == 2 && s >= 2) {
      const f16* hph = h1r + (size_t)((s + 5) & 7) * HSLOT;  // h1[s-3]
      const f16* hpl = hph + 131072;
      f16* hoh = h1r + (size_t)((s + 6) & 7) * HSLOT;        // h1[s-2]
      f16* hol = hoh + 131072;
      f32x4 aR = {0,0,0,0}, aZ = {0,0,0,0}, aN = {0,0,0,0};
      gemmK1024(hph, hpl, Wsh, lane, wv, aR, aZ, aN);
      const float* gp = gir + (size_t)((s + 6) & 7) * GSLOT; // gi for h0[s-2]
      f32x4 gR = *(const f32x4*)(gp + (size_t)u * 128 + b0);
      f32x4 gZ = *(const f32x4*)(gp + (size_t)(1024 + u) * 128 + b0);
      f32x4 gN = *(const f32x4*)(gp + (size_t)(2048 + u) * 128 + b0);
      f32x4 tR = aR + gR, tZ = aZ + gZ;
      gru_epilogue(tR, tZ, aN, gN, bR, bZ, bIN, bHN, hph, hpl, hoh, hol, u, b0);
    }
    fastbar(flags2, &ctrl[1], ++fp, NL, lead);
  }

  // =================== decoder prologue: ps + weight swap ====================
  if (role == 3) {
    const f16* hf = h1r + 7 * HSLOT;   // h1[511] lives in slot 7
    fc_step(hf, hf + 131072, fcW_s, fcbv, bid - 192, tid, out, pbr);
  }
  if (role == 0) {
    stage_W48(dwhh, Ubase, Wsh, tid);
    stage_wih(dwih, Ubase, wih_s, tid);
    bR = dbih[u] + dbhh[u]; bZ = dbih[1024 + u] + dbhh[1024 + u];
    bIN = dbih[2048 + u];   bHN = dbhh[2048 + u];
  }
  fastbar(flags2, &ctrl[1], ++fp, NL, lead);

  // =================== decoder: 23 free-running ticks ========================
  for (int d = 0; d < 23; ++d) {
    if (role == 0) {
      {
        int row = tid >> 2, k8 = tid & 3;
        if (k8 < 2) {
          const float* fpt = feats + ((size_t)row * 535 + 512 + d) * 16 + k8 * 8;
          float4 a = *(const float4*)fpt; float4 b = *(const float4*)(fpt + 4);
          f16x8 v;
          v[0] = (f16)a.x; v[1] = (f16)a.y; v[2] = (f16)a.z; v[3] = (f16)a.w;
          v[4] = (f16)b.x; v[5] = (f16)b.y; v[6] = (f16)b.z; v[7] = (f16)b.w;
          *(f16x8*)(xs + row * 32 + k8 * 8) = v;
        } else if (k8 == 2) {
          const float* pp = pbr + (size_t)(d & 7) * 1024 + row * 8;
          float4 a = *(const float4*)pp; float4 b = *(const float4*)(pp + 4);
          f16x8 v;
          v[0] = (f16)a.x; v[1] = (f16)a.y; v[2] = (f16)a.z; v[3] = (f16)a.w;
          v[4] = (f16)b.x; v[5] = (f16)b.y; v[6] = (f16)b.z; v[7] = (f16)b.w;
          *(f16x8*)(xs + row * 32 + 16) = v;
        }
      }
      __syncthreads();
      const f16* hph = h1r + (size_t)((d + 7) & 7) * HSLOT;  // h prev (d=0 -> slot 7)
      const f16* hpl = hph + 131072;
      f16* hoh = h1r + (size_t)(d & 7) * HSLOT;              // h new
      f16* hol = hoh + 131072;
      f32x4 aR = {0,0,0,0}, aZ = {0,0,0,0}, aN = {0,0,0,0}, aNx = {0,0,0,0};
      gemmK1024(hph, hpl, Wsh, lane, wv, aR, aZ, aN);
      gemmX(xs, wih_s, lane, wv, aR, aZ, aNx);
      gru_epilogue(aR, aZ, aN, aNx, bR, bZ, bIN, bHN, hph, hpl, hoh, hol, u, b0);
    }
    fastbar(flags2, &ctrl[1], ++fp, NL, lead);
    if (role == 3) {
      const f16* hd = h1r + (size_t)(d & 7) * HSLOT;
      fc_step(hd, hd + 131072, fcW_s, fcbv, bid - 192, tid,
              out + (size_t)(d + 1) * 1024, pbr + (size_t)((d + 1) & 7) * 1024);
    }
    fastbar(flags2, &ctrl[1], ++fp, NL, lead);
  }
}

// ------------------------------------ host -----------------------------------
extern "C" void kernel_launch(void* const* d_in, const int* in_sizes, int n_in,
                              void* d_out, int out_size, void* d_ws, size_t ws_size,
                              hipStream_t stream) {
  (void)in_sizes; (void)n_in; (void)out_size; (void)ws_size;
  gru_persist<<<NB, NT, 0, stream>>>(
      (const float*)d_in[0], (const float*)d_in[1],
      (const float*)d_in[4], (const float*)d_in[5],
      (const float*)d_in[6], (const float*)d_in[7],
      (const float*)d_in[8], (const float*)d_in[9],
      (const float*)d_in[10], (const float*)d_in[11],
      (const float*)d_in[12], (const float*)d_in[13],
      (const float*)d_in[14], (const float*)d_in[15],
      (const float*)d_in[16], (const float*)d_in[17],
      (float*)d_out, (char*)d_ws);
}